// Round 2
// baseline (375.070 us; speedup 1.0000x reference)
//
#include <hip/hip_runtime.h>
#include <math.h>

#define BB 8
#define CC 256
#define CQ 32
#define NN 2304   // 48*48
#define NT 36     // NN/64
#define NJ 36

typedef __attribute__((ext_vector_type(8))) short bf16x8;
typedef __attribute__((ext_vector_type(4))) float f32x4;
typedef __attribute__((ext_vector_type(4))) unsigned short u16x4;
typedef unsigned short ushort_t;
typedef unsigned int u32;

#define LOG2E 1.44269504088896f

static __device__ inline unsigned short f2bf(float f) {
    unsigned u = __builtin_bit_cast(unsigned, f);
    return (unsigned short)((u + 0x7fffu + ((u >> 16) & 1u)) >> 16);
}

// workspace layout (ushort units):
//  qx @ 0, kx @ S8, qy @ 2*S8, ky @ 3*S8          (each B*N*32, pixel-major bf16)
//  vx @ 4*S8, vy @ 4*S8+SV                        (each B*C*N, channel-major bf16, LINEAR)
//  Wall @ 4*S8+2*SV : [2][320][256] bf16          (rows 0-31 Wq*log2e, 32-63 Wk, 64-319 Wv)
//  ball  @ +163840  : [2][320] float biases       (q rows scaled by log2e)
#define S8  ((size_t)BB * NN * CQ)
#define SV  ((size_t)BB * NN * CC)
#define WOFF (4 * S8 + 2 * SV)

// ---------------------------------------------------------------------------
// Weight convert: fp32 -> bf16, fold log2(e) into Wq/bq.
// ---------------------------------------------------------------------------
__global__ __launch_bounds__(256) void wcvt_kernel(
    const float* __restrict__ wqx, const float* __restrict__ bqx,
    const float* __restrict__ wkx, const float* __restrict__ bkx,
    const float* __restrict__ wvx, const float* __restrict__ bvx,
    const float* __restrict__ wqy, const float* __restrict__ bqy,
    const float* __restrict__ wky, const float* __restrict__ bky,
    const float* __restrict__ wvy, const float* __restrict__ bvy,
    ushort_t* __restrict__ ws)
{
    ushort_t* Wall = ws + WOFF;
    float*    ball = (float*)(ws + WOFF + 2 * 320 * 256);

    int id = blockIdx.x * 256 + threadIdx.x;   // 0..40959
    int row = id >> 6;                          // 0..639
    int c4  = (id & 63) * 4;
    int br  = row >= 320;
    int r   = row - br * 320;

    const float* src;
    float scale = 1.0f;
    if (r < 32)      { src = (br ? wqy : wqx) + (size_t)r * CC;        scale = LOG2E; }
    else if (r < 64) { src = (br ? wky : wkx) + (size_t)(r - 32) * CC; }
    else             { src = (br ? wvy : wvx) + (size_t)(r - 64) * CC; }

    float4 v = *(const float4*)(src + c4);
    u16x4 pk;
    pk[0] = f2bf(v.x * scale); pk[1] = f2bf(v.y * scale);
    pk[2] = f2bf(v.z * scale); pk[3] = f2bf(v.w * scale);
    *(u16x4*)(Wall + (size_t)row * CC + c4) = pk;

    if (id < 640) {
        int row2 = id, br2 = row2 >= 320, r2 = row2 - br2 * 320;
        const float* bsrc; float sc2 = 1.0f;
        if (r2 < 32)      { bsrc = (br2 ? bqy : bqx) + r2;        sc2 = LOG2E; }
        else if (r2 < 64) { bsrc = (br2 ? bky : bkx) + (r2 - 32); }
        else              { bsrc = (br2 ? bvy : bvx) + (r2 - 64); }
        ball[row2] = bsrc[0] * sc2;
    }
}

// ---------------------------------------------------------------------------
// Projection via MFMA: block = (b, br, 64-px tile), 4 waves x 16 px, all 320
// outputs. A-frags gathered from fp32 x/y (cvt bf16); B-frags = Wall (global).
// V epilogue: LDS transpose with +4 row pad (68) -> LINEAR [c][N] global V.
// ---------------------------------------------------------------------------
__global__ __launch_bounds__(256, 2) void proj_kernel(
    const float* __restrict__ x, const float* __restrict__ y,
    ushort_t* __restrict__ ws)
{
    __shared__ __align__(16) ushort_t vls[256 * 68];   // 34 KB, padded rows

    const int t = threadIdx.x, w = t >> 6, lane = t & 63;
    const int l15 = lane & 15, quad = lane >> 4;

    const int id   = blockIdx.x;        // 0..575
    const int b    = id & 7;
    const int rest = id >> 3;           // 0..71
    const int br   = rest >= NT;
    const int tile = br ? rest - NT : rest;

    const float* src = br ? y : x;
    const ushort_t* Wall = ws + WOFF + (size_t)br * 320 * CC;
    const float*    ball = (float*)(ws + WOFF + 2 * 320 * 256) + br * 320;

    ushort_t* qbuf = ws + (size_t)br * 2 * S8;
    ushort_t* kbuf = qbuf + S8;
    ushort_t* vbufg = ws + 4 * S8 + (size_t)br * SV;

    const int px0 = tile * 64 + w * 16;

    // ---- A fragments: X^T[px][c] in bf16, 8 k-chunks ----
    const float* ap = src + (size_t)b * CC * NN + px0 + l15;
    bf16x8 af[8];
#pragma unroll
    for (int q = 0; q < 8; q++) {
        float av[8];
#pragma unroll
        for (int j = 0; j < 8; j++)
            av[j] = ap[(size_t)(q * 32 + quad * 8 + j) * NN];
        union { bf16x8 v; unsigned short u[8]; } tmp;
#pragma unroll
        for (int j = 0; j < 8; j++) tmp.u[j] = f2bf(av[j]);
        af[q] = tmp.v;
    }

    // ---- 20 output tiles x 8 K-chunk MFMAs ----
    const ushort_t* wb = Wall + (size_t)l15 * CC + quad * 8;
    f32x4 acc[20];
#pragma unroll
    for (int ot = 0; ot < 20; ot++) {
        f32x4 a = (f32x4){0.f, 0.f, 0.f, 0.f};
#pragma unroll
        for (int q = 0; q < 8; q++)
            a = __builtin_amdgcn_mfma_f32_16x16x32_bf16(
                    af[q], *(const bf16x8*)(wb + (size_t)(ot * 16) * CC + q * 32),
                    a, 0, 0, 0);
        acc[ot] = a;
    }

    // ---- epilogue: q/k direct, v via padded LDS transpose ----
#pragma unroll
    for (int ot = 0; ot < 4; ot++) {
        int o = ot * 16 + l15;          // 0..63
        float bias = ball[o];
        ushort_t* dst = (o < 32 ? qbuf : kbuf);
        int oc = o & 31;
#pragma unroll
        for (int r = 0; r < 4; r++) {
            int pxl = w * 16 + quad * 4 + r;
            dst[((size_t)b * NN + tile * 64 + pxl) * CQ + oc] = f2bf(acc[ot][r] + bias);
        }
    }
#pragma unroll
    for (int ot = 4; ot < 20; ot++) {
        int o_loc = (ot - 4) * 16 + l15;   // 0..255
        float bias = ball[64 + o_loc];
#pragma unroll
        for (int r = 0; r < 4; r++) {
            int pxl = w * 16 + quad * 4 + r;
            vls[o_loc * 68 + pxl] = f2bf(acc[ot][r] + bias);
        }
    }
    __syncthreads();
#pragma unroll
    for (int rep = 0; rep < 8; rep++) {
        int cid = rep * 256 + t;           // 0..2047
        int o_loc = cid >> 3, pc = cid & 7;
        *(uint4*)(vbufg + ((size_t)b * CC + o_loc) * NN + tile * 64 + pc * 8) =
            *(uint4*)&vls[o_loc * 68 + pc * 8];
    }
}

// ---------------------------------------------------------------------------
// Flash attention, no-max softmax (p = 2^s).
// v3: V read DIRECTLY from global (L2-resident) into a register double-buffer
// one j-tile ahead -- no V LDS, no gld_lds, no manual vmcnt. LDS holds only
// the cross-wave P tile (double-buffered, XOR-swizzled) -> one raw barrier
// per iteration. Epilogue: direct f32x4 global stores (4-quad 64B segments),
// residual in-register, no LDS round-trip.
// ---------------------------------------------------------------------------
#define TI 64
#define TJ 64

__global__ __launch_bounds__(256, 2) void flash_kernel(
    const float* __restrict__ x, const float* __restrict__ y,
    const float* __restrict__ gxp, const float* __restrict__ gyp,
    const ushort_t* __restrict__ ws, float* __restrict__ out)
{
    __shared__ __align__(16) ushort_t Ps[2][64 * 64];    // 16 KB, dbuf + XOR swizzle
    __shared__ __align__(16) float Lrow[64];

    const int t = threadIdx.x, w = t >> 6, lane = t & 63;
    const int l15 = lane & 15, quad = lane >> 4;

    const int id   = blockIdx.x;        // 0..575
    const int b    = id & 7;
    const int rest = id >> 3;
    const int br   = rest >= NT;
    const int it   = br ? rest - NT : rest;
    const int i0   = it * TI;

    const ushort_t* Qb = ws + (br ? 0 : 2 * S8);   // br0: qy/ky, br1: qx/kx
    const ushort_t* Kb = Qb + S8;
    const ushort_t* Vb = ws + 4 * S8 + (br ? SV : 0);
    const float* res = br ? y : x;
    const float gamma = br ? gyp[0] : gxp[0];
    float* op = out + (size_t)br * SV + (size_t)b * CC * NN;

    bf16x8 qf = *(const bf16x8*)(Qb + ((size_t)b * NN + i0 + w * 16 + l15) * CQ + quad * 8);

    f32x4 acc[4][4];
#pragma unroll
    for (int i = 0; i < 4; i++)
#pragma unroll
        for (int j = 0; j < 4; j++) acc[i][j] = (f32x4){0.f, 0.f, 0.f, 0.f};
    float l_loc[4] = {0.f, 0.f, 0.f, 0.f};

    // per-lane global V base: channel row (w*64 + ct*16 + l15), chunk (ks*4+quad)
    const ushort_t* Vg = Vb + (size_t)b * CC * NN
                       + (size_t)(w * 64 + l15) * NN + quad * 8;
    const ushort_t* kp = Kb + ((size_t)b * NN + l15) * CQ + quad * 8;

// load the 8 V B-frags (2 ks x 4 ct) for j-tile T into DST
#define LOAD_VF(DST, T)                                                         \
    {                                                                           \
        _Pragma("unroll")                                                       \
        for (int ct = 0; ct < 4; ct++)                                          \
            _Pragma("unroll")                                                   \
            for (int ks = 0; ks < 2; ks++)                                      \
                DST[ks * 4 + ct] = *(const bf16x8*)(Vg                          \
                    + (size_t)(ct * 16) * NN + (size_t)(T) * TJ + ks * 32);     \
    }

    // prologue: vf(0), kf(0), kf(1), S(0)
    bf16x8 vfA[8], vfB[8];
    LOAD_VF(vfA, 0)
    bf16x8 kfA[4], kfB[4];
#pragma unroll
    for (int n = 0; n < 4; n++)
        kfA[n] = *(const bf16x8*)(kp + (size_t)(n * 16) * CQ);
#pragma unroll
    for (int n = 0; n < 4; n++)
        kfB[n] = *(const bf16x8*)(kp + (size_t)(TJ + n * 16) * CQ);

    f32x4 sP[4];
#pragma unroll
    for (int n = 0; n < 4; n++)
        sP[n] = __builtin_amdgcn_mfma_f32_16x16x32_bf16(
                    qf, kfA[n], (f32x4){0.f, 0.f, 0.f, 0.f}, 0, 0, 0);

// One j-iteration. KFQK = kf(JT+1) (pipelined QK), KFLD = dest for kf(JT+2).
// VFC = vf(JT) (consumed by PV), VFN = dest for vf(JT+1). CUR = JT&1 literal.
#define FLASH_ITER(JT, CUR, KFQK, KFLD, VFC, VFN)                               \
    {                                                                           \
        /* issue next-tile register prefetches (latency hidden under iter) */   \
        if ((JT) + 1 < NJ) LOAD_VF(VFN, (JT) + 1)                               \
        if ((JT) + 2 < NJ) {                                                    \
            const ushort_t* kn = kp + (size_t)(((JT) + 2) * TJ) * CQ;           \
            _Pragma("unroll")                                                   \
            for (int n = 0; n < 4; n++)                                         \
                KFLD[n] = *(const bf16x8*)(kn + (size_t)(n * 16) * CQ);         \
        }                                                                       \
        /* p = 2^s from sP (=S(JT)), row-sum accumulate, bf16 pack */           \
        unsigned short pu[4][4];                                                \
        _Pragma("unroll")                                                       \
        for (int n = 0; n < 4; n++)                                             \
            _Pragma("unroll")                                                   \
            for (int r = 0; r < 4; r++) {                                       \
                float p = __builtin_amdgcn_exp2f(sP[n][r]);                     \
                l_loc[r] += p;                                                  \
                pu[n][r] = f2bf(p);                                             \
            }                                                                   \
        /* Ps[CUR] write, XOR-swizzled 8-col chunks (conflict-free reads) */    \
        _Pragma("unroll")                                                       \
        for (int n = 0; n < 4; n++)                                             \
            _Pragma("unroll")                                                   \
            for (int r = 0; r < 4; r++) {                                       \
                int row = w * 16 + quad * 4 + r;                                \
                int ch  = (n * 2 + (l15 >> 3)) ^ (row & 7);                     \
                Ps[CUR][row * 64 + ch * 8 + (l15 & 7)] = pu[n][r];              \
            }                                                                   \
        /* pipelined QK(JT+1): reg-only, fills the barrier shadow */            \
        if ((JT) + 1 < NJ) {                                                    \
            _Pragma("unroll")                                                   \
            for (int n = 0; n < 4; n++)                                         \
                sP[n] = __builtin_amdgcn_mfma_f32_16x16x32_bf16(                \
                    qf, KFQK[n], (f32x4){0.f, 0.f, 0.f, 0.f}, 0, 0, 0);         \
        }                                                                       \
        /* own Ps writes visible, then raw barrier (NO vmcnt drain) */          \
        asm volatile("s_waitcnt lgkmcnt(0)" ::: "memory");                      \
        __builtin_amdgcn_s_barrier();                                           \
        /* PV: 32 MFMAs from Ps[CUR] + VFC regs (compiler emits counted */      \
        /* vmcnt for VFC: 12 newer prefetch ops stay in flight) */              \
        _Pragma("unroll")                                                       \
        for (int ks = 0; ks < 2; ks++) {                                        \
            bf16x8 pf[4];                                                       \
            _Pragma("unroll")                                                   \
            for (int rt = 0; rt < 4; rt++) {                                    \
                int prow = rt * 16 + l15;                                       \
                int pch  = (ks * 4 + quad) ^ (l15 & 7);                         \
                pf[rt] = *(const bf16x8*)&Ps[CUR][prow * 64 + pch * 8];         \
            }                                                                   \
            __builtin_amdgcn_s_setprio(1);                                      \
            _Pragma("unroll")                                                   \
            for (int rt = 0; rt < 4; rt++)                                      \
                _Pragma("unroll")                                               \
                for (int ct = 0; ct < 4; ct++)                                  \
                    acc[rt][ct] = __builtin_amdgcn_mfma_f32_16x16x32_bf16(      \
                        pf[rt], VFC[ks * 4 + ct], acc[rt][ct], 0, 0, 0);        \
            __builtin_amdgcn_s_setprio(0);                                      \
        }                                                                       \
    }

    for (int jt = 0; jt < NJ; jt += 2) {
        FLASH_ITER(jt,     0, kfB, kfA, vfA, vfB)
        FLASH_ITER(jt + 1, 1, kfA, kfB, vfB, vfA)
    }
#undef FLASH_ITER
#undef LOAD_VF

    // final row-sum reduction across l15
#pragma unroll
    for (int r = 0; r < 4; r++) {
        float l = l_loc[r];
        l += __shfl_xor(l, 1);
        l += __shfl_xor(l, 2);
        l += __shfl_xor(l, 4);
        l += __shfl_xor(l, 8);
        l_loc[r] = l;
    }
    if (l15 == 0) {
        f32x4 lv = {l_loc[0], l_loc[1], l_loc[2], l_loc[3]};
        *(f32x4*)&Lrow[w * 16 + quad * 4] = lv;
    }
    __syncthreads();

    // epilogue: normalize, gamma, residual, direct f32x4 stores
    // lane (quad,l15), tile (rt,ct): rows c = w*64+ct*16+l15,
    // cols i0 + rt*16 + quad*4 + r  -> 4-quad-contiguous 64B segments.
#pragma unroll
    for (int rt = 0; rt < 4; rt++) {
        f32x4 lv = *(f32x4*)&Lrow[rt * 16 + quad * 4];
        f32x4 gi;
#pragma unroll
        for (int r = 0; r < 4; r++) gi[r] = gamma / lv[r];
#pragma unroll
        for (int ct = 0; ct < 4; ct++) {
            int c = w * 64 + ct * 16 + l15;
            size_t off = (size_t)c * NN + i0 + rt * 16 + quad * 4;
            f32x4 r4 = *(const f32x4*)&res[(size_t)b * CC * NN + off];
            f32x4 ov;
#pragma unroll
            for (int r = 0; r < 4; r++) ov[r] = acc[rt][ct][r] * gi[r] + r4[r];
            *(f32x4*)&op[off] = ov;
        }
    }
}

extern "C" void kernel_launch(void* const* d_in, const int* in_sizes, int n_in,
                              void* d_out, int out_size, void* d_ws, size_t ws_size,
                              hipStream_t stream)
{
    const float* x   = (const float*)d_in[0];
    const float* y   = (const float*)d_in[1];
    const float* wqx = (const float*)d_in[2];
    const float* bqx = (const float*)d_in[3];
    const float* wkx = (const float*)d_in[4];
    const float* bkx = (const float*)d_in[5];
    const float* wvx = (const float*)d_in[6];
    const float* bvx = (const float*)d_in[7];
    const float* wqy = (const float*)d_in[8];
    const float* bqy = (const float*)d_in[9];
    const float* wky = (const float*)d_in[10];
    const float* bky = (const float*)d_in[11];
    const float* wvy = (const float*)d_in[12];
    const float* bvy = (const float*)d_in[13];
    const float* gx  = (const float*)d_in[14];
    const float* gy  = (const float*)d_in[15];
    ushort_t* ws = (ushort_t*)d_ws;
    float* out = (float*)d_out;

    wcvt_kernel<<<dim3(160), 256, 0, stream>>>(wqx, bqx, wkx, bkx, wvx, bvx,
                                               wqy, bqy, wky, bky, wvy, bvy, ws);
    proj_kernel<<<dim3(576), 256, 0, stream>>>(x, y, ws);
    flash_kernel<<<dim3(576), 256, 0, stream>>>(x, y, gx, gy, ws, out);
}

// Round 3
// 264.936 us; speedup vs baseline: 1.4157x; 1.4157x over previous
//
#include <hip/hip_runtime.h>
#include <math.h>

#define BB 8
#define CC 256
#define CQ 32
#define NN 2304   // 48*48
#define NT 36     // NN/64
#define NJ 36

typedef __attribute__((ext_vector_type(8))) short bf16x8;
typedef __attribute__((ext_vector_type(4))) float f32x4;
typedef __attribute__((ext_vector_type(4))) unsigned short u16x4;
typedef unsigned short ushort_t;
typedef unsigned int u32;

#define LOG2E 1.44269504088896f

static __device__ inline unsigned short f2bf(float f) {
    unsigned u = __builtin_bit_cast(unsigned, f);
    return (unsigned short)((u + 0x7fffu + ((u >> 16) & 1u)) >> 16);
}

static __device__ inline void gld_lds16(const ushort_t* g, ushort_t* l) {
    __builtin_amdgcn_global_load_lds(
        (const __attribute__((address_space(1))) u32*)g,
        (__attribute__((address_space(3))) u32*)l, 16, 0, 0);
}

// workspace layout (ushort units):
//  qx @ 0, kx @ S8, qy @ 2*S8, ky @ 3*S8          (each B*N*32, pixel-major bf16)
//  vx @ 4*S8, vy @ 4*S8+SV                        (each B*C*N, channel-major bf16,
//                                                  16B chunks XOR-swizzled by c&7 per 64px tile)
//  Wall @ 4*S8+2*SV : [2][320][256] bf16          (rows 0-31 Wq*log2e, 32-63 Wk, 64-319 Wv)
//  ball  @ +163840  : [2][320] float biases       (q rows scaled by log2e)
#define S8  ((size_t)BB * NN * CQ)
#define SV  ((size_t)BB * NN * CC)
#define WOFF (4 * S8 + 2 * SV)

// ---------------------------------------------------------------------------
// Weight convert: fp32 -> bf16, fold log2(e) into Wq/bq.
// ---------------------------------------------------------------------------
__global__ __launch_bounds__(256) void wcvt_kernel(
    const float* __restrict__ wqx, const float* __restrict__ bqx,
    const float* __restrict__ wkx, const float* __restrict__ bkx,
    const float* __restrict__ wvx, const float* __restrict__ bvx,
    const float* __restrict__ wqy, const float* __restrict__ bqy,
    const float* __restrict__ wky, const float* __restrict__ bky,
    const float* __restrict__ wvy, const float* __restrict__ bvy,
    ushort_t* __restrict__ ws)
{
    ushort_t* Wall = ws + WOFF;
    float*    ball = (float*)(ws + WOFF + 2 * 320 * 256);

    int id = blockIdx.x * 256 + threadIdx.x;   // 0..40959
    int row = id >> 6;                          // 0..639
    int c4  = (id & 63) * 4;
    int br  = row >= 320;
    int r   = row - br * 320;

    const float* src;
    float scale = 1.0f;
    if (r < 32)      { src = (br ? wqy : wqx) + (size_t)r * CC;        scale = LOG2E; }
    else if (r < 64) { src = (br ? wky : wkx) + (size_t)(r - 32) * CC; }
    else             { src = (br ? wvy : wvx) + (size_t)(r - 64) * CC; }

    float4 v = *(const float4*)(src + c4);
    u16x4 pk;
    pk[0] = f2bf(v.x * scale); pk[1] = f2bf(v.y * scale);
    pk[2] = f2bf(v.z * scale); pk[3] = f2bf(v.w * scale);
    *(u16x4*)(Wall + (size_t)row * CC + c4) = pk;

    if (id < 640) {
        int row2 = id, br2 = row2 >= 320, r2 = row2 - br2 * 320;
        const float* bsrc; float sc2 = 1.0f;
        if (r2 < 32)      { bsrc = (br2 ? bqy : bqx) + r2;        sc2 = LOG2E; }
        else if (r2 < 64) { bsrc = (br2 ? bky : bkx) + (r2 - 32); }
        else              { bsrc = (br2 ? bvy : bvx) + (r2 - 64); }
        ball[row2] = bsrc[0] * sc2;
    }
}

// ---------------------------------------------------------------------------
// Projection via MFMA: block = (b, br, 64-px tile), 4 waves x 16 px, all 320
// outputs. v4: A-tile staged to LDS via coalesced float4 loads (was: 64
// scalar strided f32 loads per thread); A-frags assembled from LDS.
// scratch LDS is time-shared with the V-transpose epilogue.
// ---------------------------------------------------------------------------
__global__ __launch_bounds__(256, 2) void proj_kernel(
    const float* __restrict__ x, const float* __restrict__ y,
    ushort_t* __restrict__ ws)
{
    // phase 1: A-stage [256 c][68 px-padded] bf16 (34 KB)
    // phase 2: V-transpose (first 256*64 entries, v2 swizzled layout)
    __shared__ __align__(16) ushort_t scratch[256 * 68];

    const int t = threadIdx.x, w = t >> 6, lane = t & 63;
    const int l15 = lane & 15, quad = lane >> 4;

    const int id   = blockIdx.x;        // 0..575
    const int b    = id & 7;
    const int rest = id >> 3;           // 0..71
    const int br   = rest >= NT;
    const int tile = br ? rest - NT : rest;

    const float* src = br ? y : x;
    const ushort_t* Wall = ws + WOFF + (size_t)br * 320 * CC;
    const float*    ball = (float*)(ws + WOFF + 2 * 320 * 256) + br * 320;

    ushort_t* qbuf = ws + (size_t)br * 2 * S8;
    ushort_t* kbuf = qbuf + S8;
    ushort_t* vbufg = ws + 4 * S8 + (size_t)br * SV;

    // ---- stage A (64 px x 256 c) to LDS, coalesced float4 ----
    {
        const float* ab = src + (size_t)b * CC * NN + tile * 64;
#pragma unroll
        for (int i = 0; i < 16; i++) {
            int c  = i * 16 + (t >> 4);
            int px = (t & 15) * 4;
            float4 v = *(const float4*)(ab + (size_t)c * NN + px);
            u16x4 pk;
            pk[0] = f2bf(v.x); pk[1] = f2bf(v.y);
            pk[2] = f2bf(v.z); pk[3] = f2bf(v.w);
            *(u16x4*)&scratch[c * 68 + px] = pk;
        }
    }
    __syncthreads();

    // ---- A fragments: X^T[px][c] in bf16, 8 k-chunks, from LDS ----
    bf16x8 af[8];
#pragma unroll
    for (int q = 0; q < 8; q++) {
        union { bf16x8 v; unsigned short u[8]; } tmp;
#pragma unroll
        for (int j = 0; j < 8; j++)
            tmp.u[j] = scratch[(q * 32 + quad * 8 + j) * 68 + w * 16 + l15];
        af[q] = tmp.v;
    }

    // ---- 20 output tiles x 8 K-chunk MFMAs ----
    const ushort_t* wb = Wall + (size_t)l15 * CC + quad * 8;
    f32x4 acc[20];
#pragma unroll
    for (int ot = 0; ot < 20; ot++) {
        f32x4 a = (f32x4){0.f, 0.f, 0.f, 0.f};
#pragma unroll
        for (int q = 0; q < 8; q++)
            a = __builtin_amdgcn_mfma_f32_16x16x32_bf16(
                    af[q], *(const bf16x8*)(wb + (size_t)(ot * 16) * CC + q * 32),
                    a, 0, 0, 0);
        acc[ot] = a;
    }

    // ---- epilogue: q/k direct, v via LDS transpose+swizzle ----
#pragma unroll
    for (int ot = 0; ot < 4; ot++) {
        int o = ot * 16 + l15;          // 0..63
        float bias = ball[o];
        ushort_t* dst = (o < 32 ? qbuf : kbuf);
        int oc = o & 31;
#pragma unroll
        for (int r = 0; r < 4; r++) {
            int pxl = w * 16 + quad * 4 + r;
            dst[((size_t)b * NN + tile * 64 + pxl) * CQ + oc] = f2bf(acc[ot][r] + bias);
        }
    }
    __syncthreads();   // all af reads done before scratch is reused for V
#pragma unroll
    for (int ot = 4; ot < 20; ot++) {
        int o_loc = (ot - 4) * 16 + l15;   // 0..255
        float bias = ball[64 + o_loc];
#pragma unroll
        for (int r = 0; r < 4; r++) {
            int pxl = w * 16 + quad * 4 + r;
            scratch[o_loc * 64 + (((pxl >> 3) ^ (o_loc & 7)) * 8) + (pxl & 7)] =
                f2bf(acc[ot][r] + bias);
        }
    }
    __syncthreads();
#pragma unroll
    for (int rep = 0; rep < 8; rep++) {
        int cid = rep * 256 + t;           // 0..2047
        int o_loc = cid >> 3, pc = cid & 7;
        *(uint4*)(vbufg + ((size_t)b * CC + o_loc) * NN + tile * 64 + pc * 8) =
            *(uint4*)&scratch[cid * 8];
    }
}

// ---------------------------------------------------------------------------
// Flash attention, no-max softmax (p = 2^s).
// v2 (REVERTED to round-1 proven version): single raw s_barrier per j-tile
// (Ps double-buffered + XOR-swizzled), counted vmcnt (never drains the
// 12-deep V/K prefetch queue mid-loop), kf double-buffered in registers,
// QK(jt+1) pipelined into the barrier shadow.
// Hazard notes:
//  - V: each wave stages AND reads only channels [w*64,w*64+64) -> no cross-
//    wave V dependency; own `s_waitcnt vmcnt(12)` (in-order retire) suffices.
//  - Ps[cur] write(jt) vs cross-wave reads(jt-2 same buffer): separated by
//    barrier(jt-1) in every wave's program order.
// ---------------------------------------------------------------------------
#define TI 64
#define TJ 64

__global__ __launch_bounds__(256, 2) void flash_kernel(
    const float* __restrict__ x, const float* __restrict__ y,
    const float* __restrict__ gxp, const float* __restrict__ gyp,
    const ushort_t* __restrict__ ws, float* __restrict__ out)
{
    __shared__ __align__(16) ushort_t Vs[2][256 * 64];   // 64 KB, swizzled chunks
    __shared__ __align__(16) ushort_t Ps[2][64 * 64];    // 16 KB, dbuf + XOR swizzle
    float* Lrow = (float*)&Ps[0][0];                     // epilogue overlay
    float* Ob   = (float*)&Vs[0][0];                     // epilogue overlay

    const int t = threadIdx.x, w = t >> 6, lane = t & 63;
    const int l15 = lane & 15, quad = lane >> 4;

    const int id   = blockIdx.x;        // 0..575
    const int b    = id & 7;
    const int rest = id >> 3;
    const int br   = rest >= NT;
    const int it   = br ? rest - NT : rest;
    const int i0   = it * TI;

    const ushort_t* Qb = ws + (br ? 0 : 2 * S8);   // br0: qy/ky, br1: qx/kx
    const ushort_t* Kb = Qb + S8;
    const ushort_t* Vb = ws + 4 * S8 + (br ? SV : 0);
    const float* res = br ? y : x;
    const float gamma = br ? gyp[0] : gxp[0];
    float* op = out + (size_t)br * SV + (size_t)b * CC * NN;

    bf16x8 qf = *(const bf16x8*)(Qb + ((size_t)b * NN + i0 + w * 16 + l15) * CQ + quad * 8);

    f32x4 acc[4][4];
#pragma unroll
    for (int i = 0; i < 4; i++)
#pragma unroll
        for (int j = 0; j < 4; j++) acc[i][j] = (f32x4){0.f, 0.f, 0.f, 0.f};
    float l_loc[4] = {0.f, 0.f, 0.f, 0.f};

    // staging geometry: wave w stages channels [w*64, w*64+64)
    const ushort_t* Vg = Vb + (size_t)b * CC * NN
                       + (size_t)(w * 64 + (lane >> 3)) * NN + (lane & 7) * 8;
    const ushort_t* kp = Kb + ((size_t)b * NN + l15) * CQ + quad * 8;

    // prologue: V(0) stage + kf(0)/kf(1) + QK(0)
    {
        ushort_t* l = &Vs[0][(w * 64) * 64];
#pragma unroll
        for (int is = 0; is < 8; is++)
            gld_lds16(Vg + (size_t)is * 8 * NN, l + is * 512);
    }
    bf16x8 kfA[4], kfB[4];
#pragma unroll
    for (int n = 0; n < 4; n++)
        kfA[n] = *(const bf16x8*)(kp + (size_t)(n * 16) * CQ);
#pragma unroll
    for (int n = 0; n < 4; n++)
        kfB[n] = *(const bf16x8*)(kp + (size_t)(TJ + n * 16) * CQ);

    f32x4 sP[4];
#pragma unroll
    for (int n = 0; n < 4; n++)
        sP[n] = __builtin_amdgcn_mfma_f32_16x16x32_bf16(
                    qf, kfA[n], (f32x4){0.f, 0.f, 0.f, 0.f}, 0, 0, 0);

// One j-iteration. KFQK = kf(JT+1) (consumed by pipelined QK), KFLD = dest
// register buffer for kf(JT+2). CUR must be (JT&1) as a literal.
#define FLASH_ITER(JT, CUR, KFQK, KFLD)                                         \
    {                                                                           \
        /* issue V(JT+1) -> other buffer (own chunk; prev PV on it is done) */  \
        if ((JT) + 1 < NJ) {                                                    \
            ushort_t* l = &Vs[(CUR) ^ 1][(w * 64) * 64];                        \
            const ushort_t* g = Vg + (size_t)((JT) + 1) * TJ;                   \
            _Pragma("unroll")                                                   \
            for (int is = 0; is < 8; is++)                                      \
                gld_lds16(g + (size_t)is * 8 * NN, l + is * 512);               \
        }                                                                       \
        /* issue kf(JT+2) loads (its old contents consumed by QK(JT)) */        \
        if ((JT) + 2 < NJ) {                                                    \
            const ushort_t* kn = kp + (size_t)(((JT) + 2) * TJ) * CQ;           \
            _Pragma("unroll")                                                   \
            for (int n = 0; n < 4; n++)                                         \
                KFLD[n] = *(const bf16x8*)(kn + (size_t)(n * 16) * CQ);         \
        }                                                                       \
        /* p = 2^s from sP (=S(JT)), row-sum accumulate, bf16 pack */           \
        unsigned short pu[4][4];                                                \
        _Pragma("unroll")                                                       \
        for (int n = 0; n < 4; n++)                                             \
            _Pragma("unroll")                                                   \
            for (int r = 0; r < 4; r++) {                                       \
                float p = __builtin_amdgcn_exp2f(sP[n][r]);                     \
                l_loc[r] += p;                                                  \
                pu[n][r] = f2bf(p);                                             \
            }                                                                   \
        /* Ps[CUR] write, XOR-swizzled 8-col chunks (conflict-free reads) */    \
        _Pragma("unroll")                                                       \
        for (int n = 0; n < 4; n++)                                             \
            _Pragma("unroll")                                                   \
            for (int r = 0; r < 4; r++) {                                       \
                int row = w * 16 + quad * 4 + r;                                \
                int ch  = (n * 2 + (l15 >> 3)) ^ (row & 7);                     \
                Ps[CUR][row * 64 + ch * 8 + (l15 & 7)] = pu[n][r];              \
            }                                                                   \
        /* pipelined QK(JT+1): reg-only, fills the barrier shadow */            \
        if ((JT) + 1 < NJ) {                                                    \
            _Pragma("unroll")                                                   \
            for (int n = 0; n < 4; n++)                                         \
                sP[n] = __builtin_amdgcn_mfma_f32_16x16x32_bf16(                \
                    qf, KFQK[n], (f32x4){0.f, 0.f, 0.f, 0.f}, 0, 0, 0);         \
        }                                                                       \
        /* own Ps writes visible, then raw barrier (NO vmcnt drain) */          \
        asm volatile("s_waitcnt lgkmcnt(0)" ::: "memory");                      \
        __builtin_amdgcn_s_barrier();                                           \
        /* V(JT) guaranteed in LDS: retire down to the 12 ops of (JT+1/JT+2) */ \
        if ((JT) + 2 < NJ) asm volatile("s_waitcnt vmcnt(12)" ::: "memory");    \
        else               asm volatile("s_waitcnt vmcnt(0)"  ::: "memory");    \
        /* PV: 32 MFMAs from Ps + Vs[cur] */                                    \
        _Pragma("unroll")                                                       \
        for (int ks = 0; ks < 2; ks++) {                                        \
            bf16x8 pf[4], vf[4];                                                \
            _Pragma("unroll")                                                   \
            for (int rt = 0; rt < 4; rt++) {                                    \
                int prow = rt * 16 + l15;                                       \
                int pch  = (ks * 4 + quad) ^ (l15 & 7);                         \
                pf[rt] = *(const bf16x8*)&Ps[CUR][prow * 64 + pch * 8];         \
            }                                                                   \
            _Pragma("unroll")                                                   \
            for (int ct = 0; ct < 4; ct++) {                                    \
                int row = w * 64 + ct * 16 + l15;                               \
                int pc  = (ks * 4 + quad) ^ (l15 & 7);                          \
                vf[ct] = *(const bf16x8*)&Vs[CUR][row * 64 + pc * 8];           \
            }                                                                   \
            __builtin_amdgcn_s_setprio(1);                                      \
            _Pragma("unroll")                                                   \
            for (int rt = 0; rt < 4; rt++)                                      \
                _Pragma("unroll")                                               \
                for (int ct = 0; ct < 4; ct++)                                  \
                    acc[rt][ct] = __builtin_amdgcn_mfma_f32_16x16x32_bf16(      \
                        pf[rt], vf[ct], acc[rt][ct], 0, 0, 0);                  \
            __builtin_amdgcn_s_setprio(0);                                      \
        }                                                                       \
    }

    for (int jt = 0; jt < NJ; jt += 2) {
        FLASH_ITER(jt,     0, kfB, kfA)
        FLASH_ITER(jt + 1, 1, kfA, kfB)
    }
#undef FLASH_ITER

    // final row-sum reduction across l15
#pragma unroll
    for (int r = 0; r < 4; r++) {
        float l = l_loc[r];
        l += __shfl_xor(l, 1);
        l += __shfl_xor(l, 2);
        l += __shfl_xor(l, 4);
        l += __shfl_xor(l, 8);
        l_loc[r] = l;
    }
    if (l15 == 0) {
        f32x4 lv = {l_loc[0], l_loc[1], l_loc[2], l_loc[3]};
        *(f32x4*)&Lrow[w * 16 + quad * 4] = lv;
    }
    __syncthreads();

    // epilogue: normalize, gamma, residual, coalesced [C][N] store
    for (int rt = 0; rt < 4; rt++) {
        f32x4 lv = *(f32x4*)&Lrow[rt * 16 + quad * 4];
        f32x4 gi;
#pragma unroll
        for (int r = 0; r < 4; r++) gi[r] = gamma / lv[r];
#pragma unroll
        for (int ct = 0; ct < 4; ct++) {
            int c = w * 64 + ct * 16 + l15;
            f32x4 ov;
#pragma unroll
            for (int r = 0; r < 4; r++) ov[r] = acc[rt][ct][r] * gi[r];
            *(f32x4*)&Ob[c * 20 + quad * 4] = ov;
        }
        __syncthreads();
#pragma unroll
        for (int rep = 0; rep < 4; rep++) {
            int c  = rep * 64 + (t >> 2);
            int p4 = t & 3;
            f32x4 v = *(f32x4*)&Ob[c * 20 + p4 * 4];
            size_t go = ((size_t)b * CC + c) * NN + i0 + rt * 16 + p4 * 4;
            f32x4 r4 = *(const f32x4*)&res[go];
            v += r4;
            *(f32x4*)&op[(size_t)c * NN + i0 + rt * 16 + p4 * 4] = v;
        }
        __syncthreads();
    }
}

extern "C" void kernel_launch(void* const* d_in, const int* in_sizes, int n_in,
                              void* d_out, int out_size, void* d_ws, size_t ws_size,
                              hipStream_t stream)
{
    const float* x   = (const float*)d_in[0];
    const float* y   = (const float*)d_in[1];
    const float* wqx = (const float*)d_in[2];
    const float* bqx = (const float*)d_in[3];
    const float* wkx = (const float*)d_in[4];
    const float* bkx = (const float*)d_in[5];
    const float* wvx = (const float*)d_in[6];
    const float* bvx = (const float*)d_in[7];
    const float* wqy = (const float*)d_in[8];
    const float* bqy = (const float*)d_in[9];
    const float* wky = (const float*)d_in[10];
    const float* bky = (const float*)d_in[11];
    const float* wvy = (const float*)d_in[12];
    const float* bvy = (const float*)d_in[13];
    const float* gx  = (const float*)d_in[14];
    const float* gy  = (const float*)d_in[15];
    ushort_t* ws = (ushort_t*)d_ws;
    float* out = (float*)d_out;

    wcvt_kernel<<<dim3(160), 256, 0, stream>>>(wqx, bqx, wkx, bkx, wvx, bvx,
                                               wqy, bqy, wky, bky, wvy, bvy, ws);
    proj_kernel<<<dim3(576), 256, 0, stream>>>(x, y, ws);
    flash_kernel<<<dim3(576), 256, 0, stream>>>(x, y, gx, gy, ws, out);
}

// Round 4
// 216.730 us; speedup vs baseline: 1.7306x; 1.2224x over previous
//
#include <hip/hip_runtime.h>
#include <math.h>

#define BB 8
#define CC 256
#define CQ 32
#define NN 2304   // 48*48
#define NT 36     // NN/64
#define NJ 36

typedef __attribute__((ext_vector_type(8))) short bf16x8;
typedef __attribute__((ext_vector_type(4))) float f32x4;
typedef __attribute__((ext_vector_type(4))) unsigned short u16x4;
typedef unsigned short ushort_t;
typedef unsigned int u32;

#define LOG2E 1.44269504088896f

static __device__ inline unsigned short f2bf(float f) {
    unsigned u = __builtin_bit_cast(unsigned, f);
    return (unsigned short)((u + 0x7fffu + ((u >> 16) & 1u)) >> 16);
}

static __device__ inline void gld_lds16(const ushort_t* g, ushort_t* l) {
    __builtin_amdgcn_global_load_lds(
        (const __attribute__((address_space(1))) u32*)g,
        (__attribute__((address_space(3))) u32*)l, 16, 0, 0);
}

// workspace layout (ushort units):
//  qx @ 0, kx @ S8, qy @ 2*S8, ky @ 3*S8          (each B*N*32, pixel-major bf16)
//  vx @ 4*S8, vy @ 4*S8+SV                        (each B*C*N, channel-major bf16,
//                                                  16B chunks XOR-swizzled by c&7 per 64px tile)
//  Wall @ 4*S8+2*SV : [2][320][256] bf16          (rows 0-31 Wq*log2e, 32-63 Wk, 64-319 Wv;
//                                                  16B chunks XOR-swizzled: chunk16 ^= row&7,
//                                                  so proj can gld_lds linearly + ds_read swizzled)
//  ball  @ +163840  : [2][320] float biases       (q rows scaled by log2e)
#define S8  ((size_t)BB * NN * CQ)
#define SV  ((size_t)BB * NN * CC)
#define WOFF (4 * S8 + 2 * SV)

// ---------------------------------------------------------------------------
// Weight convert: fp32 -> bf16, fold log2(e) into Wq/bq.
// Writes Wall PRE-SWIZZLED: element-chunk ch16 (8 elems) of row r lands at
// chunk position ch16 ^ (r & 7). proj stages rows linearly into LDS and
// applies the same XOR on ds_read -> bank-conflict-free B-fragments.
// ---------------------------------------------------------------------------
__global__ __launch_bounds__(256) void wcvt_kernel(
    const float* __restrict__ wqx, const float* __restrict__ bqx,
    const float* __restrict__ wkx, const float* __restrict__ bkx,
    const float* __restrict__ wvx, const float* __restrict__ bvx,
    const float* __restrict__ wqy, const float* __restrict__ bqy,
    const float* __restrict__ wky, const float* __restrict__ bky,
    const float* __restrict__ wvy, const float* __restrict__ bvy,
    ushort_t* __restrict__ ws)
{
    ushort_t* Wall = ws + WOFF;
    float*    ball = (float*)(ws + WOFF + 2 * 320 * 256);

    int id = blockIdx.x * 256 + threadIdx.x;   // 0..40959
    int row = id >> 6;                          // 0..639
    int c4  = (id & 63) * 4;
    int br  = row >= 320;
    int r   = row - br * 320;

    const float* src;
    float scale = 1.0f;
    if (r < 32)      { src = (br ? wqy : wqx) + (size_t)r * CC;        scale = LOG2E; }
    else if (r < 64) { src = (br ? wky : wkx) + (size_t)(r - 32) * CC; }
    else             { src = (br ? wvy : wvx) + (size_t)(r - 64) * CC; }

    float4 v = *(const float4*)(src + c4);
    u16x4 pk;
    pk[0] = f2bf(v.x * scale); pk[1] = f2bf(v.y * scale);
    pk[2] = f2bf(v.z * scale); pk[3] = f2bf(v.w * scale);
    // swizzled destination: 16B chunk (c4>>3) -> (c4>>3) ^ (row&7); keep 8B half
    int ch16 = c4 >> 3;
    int half = (c4 >> 2) & 1;
    int dcol = (((ch16 ^ (row & 7)) << 3) + (half << 2));
    *(u16x4*)(Wall + (size_t)row * CC + dcol) = pk;

    if (id < 640) {
        int row2 = id, br2 = row2 >= 320, r2 = row2 - br2 * 320;
        const float* bsrc; float sc2 = 1.0f;
        if (r2 < 32)      { bsrc = (br2 ? bqy : bqx) + r2;        sc2 = LOG2E; }
        else if (r2 < 64) { bsrc = (br2 ? bky : bkx) + (r2 - 32); }
        else              { bsrc = (br2 ? bvy : bvx) + (r2 - 64); }
        ball[row2] = bsrc[0] * sc2;
    }
}

// ---------------------------------------------------------------------------
// Projection via MFMA: block = (b, br, 64-px tile), 4 waves x 16 px, all 320
// outputs. v5: W staged through LDS in 5 double-buffered 64-row chunks via
// global_load_lds (counted vmcnt(8): next chunk's 8 loads stay in flight
// across barriers). Was: every wave streamed all 160 KB of W from L2 as
// global B-frags (640 KB/block, latency-bound). A-frags: proven v2 strided
// global gather. B-frags: ds_read_b128, conflict-free via the Wall swizzle.
// ---------------------------------------------------------------------------
__global__ __launch_bounds__(256, 2) void proj_kernel(
    const float* __restrict__ x, const float* __restrict__ y,
    ushort_t* __restrict__ ws)
{
    __shared__ __align__(16) ushort_t Wls[2][64 * 256];   // 2 x 32 KB W chunks
    // epilogue V-transpose reuses Wls[0] (16384 ushorts, v2 swizzled layout)

    const int t = threadIdx.x, w = t >> 6, lane = t & 63;
    const int l15 = lane & 15, quad = lane >> 4;

    const int id   = blockIdx.x;        // 0..575
    const int b    = id & 7;
    const int rest = id >> 3;           // 0..71
    const int br   = rest >= NT;
    const int tile = br ? rest - NT : rest;

    const float* src = br ? y : x;
    const ushort_t* Wall = ws + WOFF + (size_t)br * 320 * CC;
    const float*    ball = (float*)(ws + WOFF + 2 * 320 * 256) + br * 320;

    ushort_t* qbuf = ws + (size_t)br * 2 * S8;
    ushort_t* kbuf = qbuf + S8;
    ushort_t* vbufg = ws + 4 * S8 + (size_t)br * SV;

    const int px0 = tile * 64 + w * 16;

// stage 64-row W chunk CH into Wls[BUF]: 8 rounds x 256 threads x 16B = 32 KB
#define STAGE_W(CH, BUF)                                                        \
    {                                                                           \
        const ushort_t* g = Wall + (size_t)(CH) * (64 * CC);                    \
        _Pragma("unroll")                                                       \
        for (int i = 0; i < 8; i++)                                             \
            gld_lds16(g + (size_t)(i * 256 + w * 64 + lane) * 8,                \
                      &Wls[BUF][(i * 256 + w * 64) * 8]);                       \
    }

    STAGE_W(0, 0)

    // ---- A fragments: X^T[px][c] in bf16, 8 k-chunks (strided gather) ----
    const float* ap = src + (size_t)b * CC * NN + px0 + l15;
    bf16x8 af[8];
#pragma unroll
    for (int q = 0; q < 8; q++) {
        float av[8];
#pragma unroll
        for (int j = 0; j < 8; j++)
            av[j] = ap[(size_t)(q * 32 + quad * 8 + j) * NN];
        union { bf16x8 v; unsigned short u[8]; } tmp;
#pragma unroll
        for (int j = 0; j < 8; j++) tmp.u[j] = f2bf(av[j]);
        af[q] = tmp.v;
    }

    // ---- 5 chunks x (4 ot x 8 K) MFMAs, W from LDS double-buffer ----
    f32x4 acc[20];
    const int rx = l15 & 7;   // swizzle key: (row&7) == (l15&7) since 16|ot*16

// one chunk: prefetch next, counted-vmcnt rendezvous, 4 independent acc chains
#define PROJ_CHUNK(CH, BUF)                                                     \
    {                                                                           \
        if ((CH) + 1 < 5) STAGE_W((CH) + 1, ((CH) + 1) & 1)                     \
        if ((CH) + 1 < 5) asm volatile("s_waitcnt vmcnt(8)" ::: "memory");      \
        else              asm volatile("s_waitcnt vmcnt(0)" ::: "memory");      \
        __builtin_amdgcn_s_barrier();                                           \
        const ushort_t* w0 = &Wls[BUF][(size_t)(0 * 16 + l15) * 256];           \
        const ushort_t* w1 = &Wls[BUF][(size_t)(1 * 16 + l15) * 256];           \
        const ushort_t* w2 = &Wls[BUF][(size_t)(2 * 16 + l15) * 256];           \
        const ushort_t* w3 = &Wls[BUF][(size_t)(3 * 16 + l15) * 256];           \
        f32x4 a0 = (f32x4){0.f, 0.f, 0.f, 0.f};                                 \
        f32x4 a1 = a0, a2 = a0, a3 = a0;                                        \
        _Pragma("unroll")                                                       \
        for (int q = 0; q < 8; q++) {                                           \
            int co = ((q * 4 + quad) ^ rx) << 3;                                \
            bf16x8 b0 = *(const bf16x8*)(w0 + co);                              \
            bf16x8 b1 = *(const bf16x8*)(w1 + co);                              \
            bf16x8 b2 = *(const bf16x8*)(w2 + co);                              \
            bf16x8 b3 = *(const bf16x8*)(w3 + co);                              \
            a0 = __builtin_amdgcn_mfma_f32_16x16x32_bf16(af[q], b0, a0, 0,0,0); \
            a1 = __builtin_amdgcn_mfma_f32_16x16x32_bf16(af[q], b1, a1, 0,0,0); \
            a2 = __builtin_amdgcn_mfma_f32_16x16x32_bf16(af[q], b2, a2, 0,0,0); \
            a3 = __builtin_amdgcn_mfma_f32_16x16x32_bf16(af[q], b3, a3, 0,0,0); \
        }                                                                       \
        acc[(CH) * 4 + 0] = a0; acc[(CH) * 4 + 1] = a1;                         \
        acc[(CH) * 4 + 2] = a2; acc[(CH) * 4 + 3] = a3;                         \
        __builtin_amdgcn_s_barrier();                                           \
    }

    PROJ_CHUNK(0, 0)
    PROJ_CHUNK(1, 1)
    PROJ_CHUNK(2, 0)
    PROJ_CHUNK(3, 1)
    PROJ_CHUNK(4, 0)
#undef PROJ_CHUNK
#undef STAGE_W

    // ---- epilogue: q/k direct, v via LDS transpose+swizzle (reuse Wls[0]) ----
    ushort_t* scratch = &Wls[0][0];
#pragma unroll
    for (int ot = 0; ot < 4; ot++) {
        int o = ot * 16 + l15;          // 0..63
        float bias = ball[o];
        ushort_t* dst = (o < 32 ? qbuf : kbuf);
        int oc = o & 31;
#pragma unroll
        for (int r = 0; r < 4; r++) {
            int pxl = w * 16 + quad * 4 + r;
            dst[((size_t)b * NN + tile * 64 + pxl) * CQ + oc] = f2bf(acc[ot][r] + bias);
        }
    }
#pragma unroll
    for (int ot = 4; ot < 20; ot++) {
        int o_loc = (ot - 4) * 16 + l15;   // 0..255
        float bias = ball[64 + o_loc];
#pragma unroll
        for (int r = 0; r < 4; r++) {
            int pxl = w * 16 + quad * 4 + r;
            scratch[o_loc * 64 + (((pxl >> 3) ^ (o_loc & 7)) * 8) + (pxl & 7)] =
                f2bf(acc[ot][r] + bias);
        }
    }
    __syncthreads();
#pragma unroll
    for (int rep = 0; rep < 8; rep++) {
        int cid = rep * 256 + t;           // 0..2047
        int o_loc = cid >> 3, pc = cid & 7;
        *(uint4*)(vbufg + ((size_t)b * CC + o_loc) * NN + tile * 64 + pc * 8) =
            *(uint4*)&scratch[cid * 8];
    }
}

// ---------------------------------------------------------------------------
// Flash attention, no-max softmax (p = 2^s).
// v2 (proven, 97.2-97.6 us): single raw s_barrier per j-tile (Ps dbuf +
// XOR swizzle), counted vmcnt(12), kf reg-dbuf, QK(jt+1) in barrier shadow.
// Hazards: V wave-private (own vmcnt suffices); Ps write(jt) vs cross-wave
// read(jt-2 same buffer) separated by barrier(jt-1).
// ---------------------------------------------------------------------------
#define TI 64
#define TJ 64

__global__ __launch_bounds__(256, 2) void flash_kernel(
    const float* __restrict__ x, const float* __restrict__ y,
    const float* __restrict__ gxp, const float* __restrict__ gyp,
    const ushort_t* __restrict__ ws, float* __restrict__ out)
{
    __shared__ __align__(16) ushort_t Vs[2][256 * 64];   // 64 KB, swizzled chunks
    __shared__ __align__(16) ushort_t Ps[2][64 * 64];    // 16 KB, dbuf + XOR swizzle
    float* Lrow = (float*)&Ps[0][0];                     // epilogue overlay
    float* Ob   = (float*)&Vs[0][0];                     // epilogue overlay

    const int t = threadIdx.x, w = t >> 6, lane = t & 63;
    const int l15 = lane & 15, quad = lane >> 4;

    const int id   = blockIdx.x;        // 0..575
    const int b    = id & 7;
    const int rest = id >> 3;
    const int br   = rest >= NT;
    const int it   = br ? rest - NT : rest;
    const int i0   = it * TI;

    const ushort_t* Qb = ws + (br ? 0 : 2 * S8);   // br0: qy/ky, br1: qx/kx
    const ushort_t* Kb = Qb + S8;
    const ushort_t* Vb = ws + 4 * S8 + (br ? SV : 0);
    const float* res = br ? y : x;
    const float gamma = br ? gyp[0] : gxp[0];
    float* op = out + (size_t)br * SV + (size_t)b * CC * NN;

    bf16x8 qf = *(const bf16x8*)(Qb + ((size_t)b * NN + i0 + w * 16 + l15) * CQ + quad * 8);

    f32x4 acc[4][4];
#pragma unroll
    for (int i = 0; i < 4; i++)
#pragma unroll
        for (int j = 0; j < 4; j++) acc[i][j] = (f32x4){0.f, 0.f, 0.f, 0.f};
    float l_loc[4] = {0.f, 0.f, 0.f, 0.f};

    // staging geometry: wave w stages channels [w*64, w*64+64)
    const ushort_t* Vg = Vb + (size_t)b * CC * NN
                       + (size_t)(w * 64 + (lane >> 3)) * NN + (lane & 7) * 8;
    const ushort_t* kp = Kb + ((size_t)b * NN + l15) * CQ + quad * 8;

    // prologue: V(0) stage + kf(0)/kf(1) + QK(0)
    {
        ushort_t* l = &Vs[0][(w * 64) * 64];
#pragma unroll
        for (int is = 0; is < 8; is++)
            gld_lds16(Vg + (size_t)is * 8 * NN, l + is * 512);
    }
    bf16x8 kfA[4], kfB[4];
#pragma unroll
    for (int n = 0; n < 4; n++)
        kfA[n] = *(const bf16x8*)(kp + (size_t)(n * 16) * CQ);
#pragma unroll
    for (int n = 0; n < 4; n++)
        kfB[n] = *(const bf16x8*)(kp + (size_t)(TJ + n * 16) * CQ);

    f32x4 sP[4];
#pragma unroll
    for (int n = 0; n < 4; n++)
        sP[n] = __builtin_amdgcn_mfma_f32_16x16x32_bf16(
                    qf, kfA[n], (f32x4){0.f, 0.f, 0.f, 0.f}, 0, 0, 0);

// One j-iteration. KFQK = kf(JT+1) (consumed by pipelined QK), KFLD = dest
// register buffer for kf(JT+2). CUR must be (JT&1) as a literal.
#define FLASH_ITER(JT, CUR, KFQK, KFLD)                                         \
    {                                                                           \
        /* issue V(JT+1) -> other buffer (own chunk; prev PV on it is done) */  \
        if ((JT) + 1 < NJ) {                                                    \
            ushort_t* l = &Vs[(CUR) ^ 1][(w * 64) * 64];                        \
            const ushort_t* g = Vg + (size_t)((JT) + 1) * TJ;                   \
            _Pragma("unroll")                                                   \
            for (int is = 0; is < 8; is++)                                      \
                gld_lds16(g + (size_t)is * 8 * NN, l + is * 512);               \
        }                                                                       \
        /* issue kf(JT+2) loads (its old contents consumed by QK(JT)) */        \
        if ((JT) + 2 < NJ) {                                                    \
            const ushort_t* kn = kp + (size_t)(((JT) + 2) * TJ) * CQ;           \
            _Pragma("unroll")                                                   \
            for (int n = 0; n < 4; n++)                                         \
                KFLD[n] = *(const bf16x8*)(kn + (size_t)(n * 16) * CQ);         \
        }                                                                       \
        /* p = 2^s from sP (=S(JT)), row-sum accumulate, bf16 pack */           \
        unsigned short pu[4][4];                                                \
        _Pragma("unroll")                                                       \
        for (int n = 0; n < 4; n++)                                             \
            _Pragma("unroll")                                                   \
            for (int r = 0; r < 4; r++) {                                       \
                float p = __builtin_amdgcn_exp2f(sP[n][r]);                     \
                l_loc[r] += p;                                                  \
                pu[n][r] = f2bf(p);                                             \
            }                                                                   \
        /* Ps[CUR] write, XOR-swizzled 8-col chunks (conflict-free reads) */    \
        _Pragma("unroll")                                                       \
        for (int n = 0; n < 4; n++)                                             \
            _Pragma("unroll")                                                   \
            for (int r = 0; r < 4; r++) {                                       \
                int row = w * 16 + quad * 4 + r;                                \
                int ch  = (n * 2 + (l15 >> 3)) ^ (row & 7);                     \
                Ps[CUR][row * 64 + ch * 8 + (l15 & 7)] = pu[n][r];              \
            }                                                                   \
        /* pipelined QK(JT+1): reg-only, fills the barrier shadow */            \
        if ((JT) + 1 < NJ) {                                                    \
            _Pragma("unroll")                                                   \
            for (int n = 0; n < 4; n++)                                         \
                sP[n] = __builtin_amdgcn_mfma_f32_16x16x32_bf16(                \
                    qf, KFQK[n], (f32x4){0.f, 0.f, 0.f, 0.f}, 0, 0, 0);         \
        }                                                                       \
        /* own Ps writes visible, then raw barrier (NO vmcnt drain) */          \
        asm volatile("s_waitcnt lgkmcnt(0)" ::: "memory");                      \
        __builtin_amdgcn_s_barrier();                                           \
        /* V(JT) guaranteed in LDS: retire down to the 12 ops of (JT+1/JT+2) */ \
        if ((JT) + 2 < NJ) asm volatile("s_waitcnt vmcnt(12)" ::: "memory");    \
        else               asm volatile("s_waitcnt vmcnt(0)"  ::: "memory");    \
        /* PV: 32 MFMAs from Ps + Vs[cur] */                                    \
        _Pragma("unroll")                                                       \
        for (int ks = 0; ks < 2; ks++) {                                        \
            bf16x8 pf[4], vf[4];                                                \
            _Pragma("unroll")                                                   \
            for (int rt = 0; rt < 4; rt++) {                                    \
                int prow = rt * 16 + l15;                                       \
                int pch  = (ks * 4 + quad) ^ (l15 & 7);                         \
                pf[rt] = *(const bf16x8*)&Ps[CUR][prow * 64 + pch * 8];         \
            }                                                                   \
            _Pragma("unroll")                                                   \
            for (int ct = 0; ct < 4; ct++) {                                    \
                int row = w * 64 + ct * 16 + l15;                               \
                int pc  = (ks * 4 + quad) ^ (l15 & 7);                          \
                vf[ct] = *(const bf16x8*)&Vs[CUR][row * 64 + pc * 8];           \
            }                                                                   \
            __builtin_amdgcn_s_setprio(1);                                      \
            _Pragma("unroll")                                                   \
            for (int rt = 0; rt < 4; rt++)                                      \
                _Pragma("unroll")                                               \
                for (int ct = 0; ct < 4; ct++)                                  \
                    acc[rt][ct] = __builtin_amdgcn_mfma_f32_16x16x32_bf16(      \
                        pf[rt], vf[ct], acc[rt][ct], 0, 0, 0);                  \
            __builtin_amdgcn_s_setprio(0);                                      \
        }                                                                       \
    }

    for (int jt = 0; jt < NJ; jt += 2) {
        FLASH_ITER(jt,     0, kfB, kfA)
        FLASH_ITER(jt + 1, 1, kfA, kfB)
    }
#undef FLASH_ITER

    // final row-sum reduction across l15
#pragma unroll
    for (int r = 0; r < 4; r++) {
        float l = l_loc[r];
        l += __shfl_xor(l, 1);
        l += __shfl_xor(l, 2);
        l += __shfl_xor(l, 4);
        l += __shfl_xor(l, 8);
        l_loc[r] = l;
    }
    if (l15 == 0) {
        f32x4 lv = {l_loc[0], l_loc[1], l_loc[2], l_loc[3]};
        *(f32x4*)&Lrow[w * 16 + quad * 4] = lv;
    }
    __syncthreads();

    // epilogue: normalize, gamma, residual, coalesced [C][N] store
    for (int rt = 0; rt < 4; rt++) {
        f32x4 lv = *(f32x4*)&Lrow[rt * 16 + quad * 4];
        f32x4 gi;
#pragma unroll
        for (int r = 0; r < 4; r++) gi[r] = gamma / lv[r];
#pragma unroll
        for (int ct = 0; ct < 4; ct++) {
            int c = w * 64 + ct * 16 + l15;
            f32x4 ov;
#pragma unroll
            for (int r = 0; r < 4; r++) ov[r] = acc[rt][ct][r] * gi[r];
            *(f32x4*)&Ob[c * 20 + quad * 4] = ov;
        }
        __syncthreads();
#pragma unroll
        for (int rep = 0; rep < 4; rep++) {
            int c  = rep * 64 + (t >> 2);
            int p4 = t & 3;
            f32x4 v = *(f32x4*)&Ob[c * 20 + p4 * 4];
            size_t go = ((size_t)b * CC + c) * NN + i0 + rt * 16 + p4 * 4;
            f32x4 r4 = *(const f32x4*)&res[go];
            v += r4;
            *(f32x4*)&op[(size_t)c * NN + i0 + rt * 16 + p4 * 4] = v;
        }
        __syncthreads();
    }
}

extern "C" void kernel_launch(void* const* d_in, const int* in_sizes, int n_in,
                              void* d_out, int out_size, void* d_ws, size_t ws_size,
                              hipStream_t stream)
{
    const float* x   = (const float*)d_in[0];
    const float* y   = (const float*)d_in[1];
    const float* wqx = (const float*)d_in[2];
    const float* bqx = (const float*)d_in[3];
    const float* wkx = (const float*)d_in[4];
    const float* bkx = (const float*)d_in[5];
    const float* wvx = (const float*)d_in[6];
    const float* bvx = (const float*)d_in[7];
    const float* wqy = (const float*)d_in[8];
    const float* bqy = (const float*)d_in[9];
    const float* wky = (const float*)d_in[10];
    const float* bky = (const float*)d_in[11];
    const float* wvy = (const float*)d_in[12];
    const float* bvy = (const float*)d_in[13];
    const float* gx  = (const float*)d_in[14];
    const float* gy  = (const float*)d_in[15];
    ushort_t* ws = (ushort_t*)d_ws;
    float* out = (float*)d_out;

    wcvt_kernel<<<dim3(160), 256, 0, stream>>>(wqx, bqx, wkx, bkx, wvx, bvx,
                                               wqy, bqy, wky, bky, wvy, bvy, ws);
    proj_kernel<<<dim3(576), 256, 0, stream>>>(x, y, ws);
    flash_kernel<<<dim3(576), 256, 0, stream>>>(x, y, gx, gy, ws, out);
}

// Round 6
// 210.175 us; speedup vs baseline: 1.7846x; 1.0312x over previous
//
#include <hip/hip_runtime.h>
#include <math.h>

#define BB 8
#define CC 256
#define CQ 32
#define NN 2304   // 48*48
#define NT 36     // NN/64
#define NJ 36

typedef __attribute__((ext_vector_type(8))) short bf16x8;
typedef __attribute__((ext_vector_type(4))) float f32x4;
typedef __attribute__((ext_vector_type(4))) unsigned short u16x4;
typedef unsigned short ushort_t;
typedef unsigned int u32;

#define LOG2E 1.44269504088896f

static __device__ inline unsigned short f2bf(float f) {
    unsigned u = __builtin_bit_cast(unsigned, f);
    return (unsigned short)((u + 0x7fffu + ((u >> 16) & 1u)) >> 16);
}

static __device__ inline void gld_lds16(const ushort_t* g, ushort_t* l) {
    __builtin_amdgcn_global_load_lds(
        (const __attribute__((address_space(1))) u32*)g,
        (__attribute__((address_space(3))) u32*)l, 16, 0, 0);
}

// workspace layout (ushort units):
//  qx @ 0, kx @ S8, qy @ 2*S8, ky @ 3*S8          (each B*N*32, pixel-major bf16)
//  vx @ 4*S8, vy @ 4*S8+SV                        (each B*C*N, channel-major bf16,
//                                                  16B chunks XOR-swizzled by c&7 per 64px tile)
//  Wall @ 4*S8+2*SV : [2][320][256] bf16          (rows 0-31 Wq*log2e, 32-63 Wk, 64-319 Wv;
//                                                  16B chunks XOR-swizzled: chunk16 ^= row&7)
//  ball  @ +163840  : [2][320] float biases       (q rows scaled by log2e)
#define S8  ((size_t)BB * NN * CQ)
#define SV  ((size_t)BB * NN * CC)
#define WOFF (4 * S8 + 2 * SV)

// ---------------------------------------------------------------------------
// Weight convert: fp32 -> bf16, fold log2(e) into Wq/bq. Wall pre-swizzled.
// ---------------------------------------------------------------------------
__global__ __launch_bounds__(256) void wcvt_kernel(
    const float* __restrict__ wqx, const float* __restrict__ bqx,
    const float* __restrict__ wkx, const float* __restrict__ bkx,
    const float* __restrict__ wvx, const float* __restrict__ bvx,
    const float* __restrict__ wqy, const float* __restrict__ bqy,
    const float* __restrict__ wky, const float* __restrict__ bky,
    const float* __restrict__ wvy, const float* __restrict__ bvy,
    ushort_t* __restrict__ ws)
{
    ushort_t* Wall = ws + WOFF;
    float*    ball = (float*)(ws + WOFF + 2 * 320 * 256);

    int id = blockIdx.x * 256 + threadIdx.x;   // 0..40959
    int row = id >> 6;                          // 0..639
    int c4  = (id & 63) * 4;
    int br  = row >= 320;
    int r   = row - br * 320;

    const float* src;
    float scale = 1.0f;
    if (r < 32)      { src = (br ? wqy : wqx) + (size_t)r * CC;        scale = LOG2E; }
    else if (r < 64) { src = (br ? wky : wkx) + (size_t)(r - 32) * CC; }
    else             { src = (br ? wvy : wvx) + (size_t)(r - 64) * CC; }

    float4 v = *(const float4*)(src + c4);
    u16x4 pk;
    pk[0] = f2bf(v.x * scale); pk[1] = f2bf(v.y * scale);
    pk[2] = f2bf(v.z * scale); pk[3] = f2bf(v.w * scale);
    // swizzled destination: 16B chunk (c4>>3) -> (c4>>3) ^ (row&7); keep 8B half
    int ch16 = c4 >> 3;
    int half = (c4 >> 2) & 1;
    int dcol = (((ch16 ^ (row & 7)) << 3) + (half << 2));
    *(u16x4*)(Wall + (size_t)row * CC + dcol) = pk;

    if (id < 640) {
        int row2 = id, br2 = row2 >= 320, r2 = row2 - br2 * 320;
        const float* bsrc; float sc2 = 1.0f;
        if (r2 < 32)      { bsrc = (br2 ? bqy : bqx) + r2;        sc2 = LOG2E; }
        else if (r2 < 64) { bsrc = (br2 ? bky : bkx) + (r2 - 32); }
        else              { bsrc = (br2 ? bvy : bvx) + (r2 - 64); }
        ball[row2] = bsrc[0] * sc2;
    }
}

// ---------------------------------------------------------------------------
// Projection via MFMA. v6 (UNDER TEST this round): 32-row W chunks
// (Wls 2x16 KB = 32 KB LDS) -> 3 blocks/CU, all 576 blocks co-resident.
// 10 chunks, counted vmcnt(4). Barrier-2 at chunk end guarantees all waves'
// reads of buffer B are done before stage(CH+2) overwrites it.
// ---------------------------------------------------------------------------
__global__ __launch_bounds__(256, 3) void proj_kernel(
    const float* __restrict__ x, const float* __restrict__ y,
    ushort_t* __restrict__ ws)
{
    __shared__ __align__(16) ushort_t Wls[2][32 * 256];   // 2 x 16 KB W chunks
    // epilogue V-transpose reuses all of Wls (16384 ushorts)

    const int t = threadIdx.x, w = t >> 6, lane = t & 63;
    const int l15 = lane & 15, quad = lane >> 4;

    const int id   = blockIdx.x;        // 0..575
    const int b    = id & 7;
    const int rest = id >> 3;           // 0..71
    const int br   = rest >= NT;
    const int tile = br ? rest - NT : rest;

    const float* src = br ? y : x;
    const ushort_t* Wall = ws + WOFF + (size_t)br * 320 * CC;
    const float*    ball = (float*)(ws + WOFF + 2 * 320 * 256) + br * 320;

    ushort_t* qbuf = ws + (size_t)br * 2 * S8;
    ushort_t* kbuf = qbuf + S8;
    ushort_t* vbufg = ws + 4 * S8 + (size_t)br * SV;

    const int px0 = tile * 64 + w * 16;

// stage 32-row W chunk CH into Wls[BUF]: 4 rounds x 256 threads x 16B = 16 KB
#define STAGE_W(CH, BUF)                                                        \
    {                                                                           \
        const ushort_t* g = Wall + (size_t)(CH) * (32 * CC);                    \
        _Pragma("unroll")                                                       \
        for (int i = 0; i < 4; i++)                                             \
            gld_lds16(g + (size_t)(i * 256 + w * 64 + lane) * 8,                \
                      &Wls[BUF][(i * 256 + w * 64) * 8]);                       \
    }

    STAGE_W(0, 0)

    // ---- A fragments: X^T[px][c] in bf16, 8 k-chunks (strided gather) ----
    const float* ap = src + (size_t)b * CC * NN + px0 + l15;
    bf16x8 af[8];
#pragma unroll
    for (int q = 0; q < 8; q++) {
        float av[8];
#pragma unroll
        for (int j = 0; j < 8; j++)
            av[j] = ap[(size_t)(q * 32 + quad * 8 + j) * NN];
        union { bf16x8 v; unsigned short u[8]; } tmp;
#pragma unroll
        for (int j = 0; j < 8; j++) tmp.u[j] = f2bf(av[j]);
        af[q] = tmp.v;
    }

    // ---- 10 chunks x (2 ot x 8 K) MFMAs, W from LDS double-buffer ----
    f32x4 acc[20];
    const int rx = l15 & 7;   // swizzle key: (row&7) == (l15&7) since 16|ot*16

// one chunk: prefetch next, counted-vmcnt rendezvous, 2 acc chains
#define PROJ_CHUNK(CH, BUF)                                                     \
    {                                                                           \
        if ((CH) + 1 < 10) STAGE_W((CH) + 1, ((CH) + 1) & 1)                    \
        if ((CH) + 1 < 10) asm volatile("s_waitcnt vmcnt(4)" ::: "memory");     \
        else               asm volatile("s_waitcnt vmcnt(0)" ::: "memory");     \
        __builtin_amdgcn_s_barrier();                                           \
        const ushort_t* w0 = &Wls[BUF][(size_t)(0 * 16 + l15) * 256];           \
        const ushort_t* w1 = &Wls[BUF][(size_t)(1 * 16 + l15) * 256];           \
        f32x4 a0 = (f32x4){0.f, 0.f, 0.f, 0.f};                                 \
        f32x4 a1 = a0;                                                          \
        _Pragma("unroll")                                                       \
        for (int q = 0; q < 8; q++) {                                           \
            int co = ((q * 4 + quad) ^ rx) << 3;                                \
            bf16x8 b0 = *(const bf16x8*)(w0 + co);                              \
            bf16x8 b1 = *(const bf16x8*)(w1 + co);                              \
            a0 = __builtin_amdgcn_mfma_f32_16x16x32_bf16(af[q], b0, a0, 0,0,0); \
            a1 = __builtin_amdgcn_mfma_f32_16x16x32_bf16(af[q], b1, a1, 0,0,0); \
        }                                                                       \
        acc[(CH) * 2 + 0] = a0; acc[(CH) * 2 + 1] = a1;                         \
        __builtin_amdgcn_s_barrier();                                           \
    }

    PROJ_CHUNK(0, 0)
    PROJ_CHUNK(1, 1)
    PROJ_CHUNK(2, 0)
    PROJ_CHUNK(3, 1)
    PROJ_CHUNK(4, 0)
    PROJ_CHUNK(5, 1)
    PROJ_CHUNK(6, 0)
    PROJ_CHUNK(7, 1)
    PROJ_CHUNK(8, 0)
    PROJ_CHUNK(9, 1)
#undef PROJ_CHUNK
#undef STAGE_W

    // ---- epilogue: q/k direct, v via LDS transpose+swizzle (reuse Wls) ----
    ushort_t* scratch = &Wls[0][0];
#pragma unroll
    for (int ot = 0; ot < 4; ot++) {
        int o = ot * 16 + l15;          // 0..63
        float bias = ball[o];
        ushort_t* dst = (o < 32 ? qbuf : kbuf);
        int oc = o & 31;
#pragma unroll
        for (int r = 0; r < 4; r++) {
            int pxl = w * 16 + quad * 4 + r;
            dst[((size_t)b * NN + tile * 64 + pxl) * CQ + oc] = f2bf(acc[ot][r] + bias);
        }
    }
#pragma unroll
    for (int ot = 4; ot < 20; ot++) {
        int o_loc = (ot - 4) * 16 + l15;   // 0..255
        float bias = ball[64 + o_loc];
#pragma unroll
        for (int r = 0; r < 4; r++) {
            int pxl = w * 16 + quad * 4 + r;
            scratch[o_loc * 64 + (((pxl >> 3) ^ (o_loc & 7)) * 8) + (pxl & 7)] =
                f2bf(acc[ot][r] + bias);
        }
    }
    __syncthreads();
#pragma unroll
    for (int rep = 0; rep < 8; rep++) {
        int cid = rep * 256 + t;           // 0..2047
        int o_loc = cid >> 3, pc = cid & 7;
        *(uint4*)(vbufg + ((size_t)b * CC + o_loc) * NN + tile * 64 + pc * 8) =
            *(uint4*)&scratch[cid * 8];
    }
}

// ---------------------------------------------------------------------------
// Flash attention, no-max softmax (p = 2^s).
// v2 (REVERTED to round-4 proven version, byte-identical): single raw
// s_barrier per j-tile (Ps dbuf + XOR swizzle), counted vmcnt(12), kf
// reg-dbuf, QK(jt+1) in barrier shadow, Vs double-buffered, 2 blocks/CU.
// ---------------------------------------------------------------------------
#define TI 64
#define TJ 64

__global__ __launch_bounds__(256, 2) void flash_kernel(
    const float* __restrict__ x, const float* __restrict__ y,
    const float* __restrict__ gxp, const float* __restrict__ gyp,
    const ushort_t* __restrict__ ws, float* __restrict__ out)
{
    __shared__ __align__(16) ushort_t Vs[2][256 * 64];   // 64 KB, swizzled chunks
    __shared__ __align__(16) ushort_t Ps[2][64 * 64];    // 16 KB, dbuf + XOR swizzle
    float* Lrow = (float*)&Ps[0][0];                     // epilogue overlay
    float* Ob   = (float*)&Vs[0][0];                     // epilogue overlay

    const int t = threadIdx.x, w = t >> 6, lane = t & 63;
    const int l15 = lane & 15, quad = lane >> 4;

    const int id   = blockIdx.x;        // 0..575
    const int b    = id & 7;
    const int rest = id >> 3;
    const int br   = rest >= NT;
    const int it   = br ? rest - NT : rest;
    const int i0   = it * TI;

    const ushort_t* Qb = ws + (br ? 0 : 2 * S8);   // br0: qy/ky, br1: qx/kx
    const ushort_t* Kb = Qb + S8;
    const ushort_t* Vb = ws + 4 * S8 + (br ? SV : 0);
    const float* res = br ? y : x;
    const float gamma = br ? gyp[0] : gxp[0];
    float* op = out + (size_t)br * SV + (size_t)b * CC * NN;

    bf16x8 qf = *(const bf16x8*)(Qb + ((size_t)b * NN + i0 + w * 16 + l15) * CQ + quad * 8);

    f32x4 acc[4][4];
#pragma unroll
    for (int i = 0; i < 4; i++)
#pragma unroll
        for (int j = 0; j < 4; j++) acc[i][j] = (f32x4){0.f, 0.f, 0.f, 0.f};
    float l_loc[4] = {0.f, 0.f, 0.f, 0.f};

    // staging geometry: wave w stages channels [w*64, w*64+64)
    const ushort_t* Vg = Vb + (size_t)b * CC * NN
                       + (size_t)(w * 64 + (lane >> 3)) * NN + (lane & 7) * 8;
    const ushort_t* kp = Kb + ((size_t)b * NN + l15) * CQ + quad * 8;

    // prologue: V(0) stage + kf(0)/kf(1) + QK(0)
    {
        ushort_t* l = &Vs[0][(w * 64) * 64];
#pragma unroll
        for (int is = 0; is < 8; is++)
            gld_lds16(Vg + (size_t)is * 8 * NN, l + is * 512);
    }
    bf16x8 kfA[4], kfB[4];
#pragma unroll
    for (int n = 0; n < 4; n++)
        kfA[n] = *(const bf16x8*)(kp + (size_t)(n * 16) * CQ);
#pragma unroll
    for (int n = 0; n < 4; n++)
        kfB[n] = *(const bf16x8*)(kp + (size_t)(TJ + n * 16) * CQ);

    f32x4 sP[4];
#pragma unroll
    for (int n = 0; n < 4; n++)
        sP[n] = __builtin_amdgcn_mfma_f32_16x16x32_bf16(
                    qf, kfA[n], (f32x4){0.f, 0.f, 0.f, 0.f}, 0, 0, 0);

// One j-iteration. KFQK = kf(JT+1) (consumed by pipelined QK), KFLD = dest
// register buffer for kf(JT+2). CUR must be (JT&1) as a literal.
#define FLASH_ITER(JT, CUR, KFQK, KFLD)                                         \
    {                                                                           \
        /* issue V(JT+1) -> other buffer (own chunk; prev PV on it is done) */  \
        if ((JT) + 1 < NJ) {                                                    \
            ushort_t* l = &Vs[(CUR) ^ 1][(w * 64) * 64];                        \
            const ushort_t* g = Vg + (size_t)((JT) + 1) * TJ;                   \
            _Pragma("unroll")                                                   \
            for (int is = 0; is < 8; is++)                                      \
                gld_lds16(g + (size_t)is * 8 * NN, l + is * 512);               \
        }                                                                       \
        /* issue kf(JT+2) loads (its old contents consumed by QK(JT)) */        \
        if ((JT) + 2 < NJ) {                                                    \
            const ushort_t* kn = kp + (size_t)(((JT) + 2) * TJ) * CQ;           \
            _Pragma("unroll")                                                   \
            for (int n = 0; n < 4; n++)                                         \
                KFLD[n] = *(const bf16x8*)(kn + (size_t)(n * 16) * CQ);         \
        }                                                                       \
        /* p = 2^s from sP (=S(JT)), row-sum accumulate, bf16 pack */           \
        unsigned short pu[4][4];                                                \
        _Pragma("unroll")                                                       \
        for (int n = 0; n < 4; n++)                                             \
            _Pragma("unroll")                                                   \
            for (int r = 0; r < 4; r++) {                                       \
                float p = __builtin_amdgcn_exp2f(sP[n][r]);                     \
                l_loc[r] += p;                                                  \
                pu[n][r] = f2bf(p);                                             \
            }                                                                   \
        /* Ps[CUR] write, XOR-swizzled 8-col chunks (conflict-free reads) */    \
        _Pragma("unroll")                                                       \
        for (int n = 0; n < 4; n++)                                             \
            _Pragma("unroll")                                                   \
            for (int r = 0; r < 4; r++) {                                       \
                int row = w * 16 + quad * 4 + r;                                \
                int ch  = (n * 2 + (l15 >> 3)) ^ (row & 7);                     \
                Ps[CUR][row * 64 + ch * 8 + (l15 & 7)] = pu[n][r];              \
            }                                                                   \
        /* pipelined QK(JT+1): reg-only, fills the barrier shadow */            \
        if ((JT) + 1 < NJ) {                                                    \
            _Pragma("unroll")                                                   \
            for (int n = 0; n < 4; n++)                                         \
                sP[n] = __builtin_amdgcn_mfma_f32_16x16x32_bf16(                \
                    qf, KFQK[n], (f32x4){0.f, 0.f, 0.f, 0.f}, 0, 0, 0);         \
        }                                                                       \
        /* own Ps writes visible, then raw barrier (NO vmcnt drain) */          \
        asm volatile("s_waitcnt lgkmcnt(0)" ::: "memory");                      \
        __builtin_amdgcn_s_barrier();                                           \
        /* V(JT) guaranteed in LDS: retire down to the 12 ops of (JT+1/JT+2) */ \
        if ((JT) + 2 < NJ) asm volatile("s_waitcnt vmcnt(12)" ::: "memory");    \
        else               asm volatile("s_waitcnt vmcnt(0)"  ::: "memory");    \
        /* PV: 32 MFMAs from Ps + Vs[cur] */                                    \
        _Pragma("unroll")                                                       \
        for (int ks = 0; ks < 2; ks++) {                                        \
            bf16x8 pf[4], vf[4];                                                \
            _Pragma("unroll")                                                   \
            for (int rt = 0; rt < 4; rt++) {                                    \
                int prow = rt * 16 + l15;                                       \
                int pch  = (ks * 4 + quad) ^ (l15 & 7);                         \
                pf[rt] = *(const bf16x8*)&Ps[CUR][prow * 64 + pch * 8];         \
            }                                                                   \
            _Pragma("unroll")                                                   \
            for (int ct = 0; ct < 4; ct++) {                                    \
                int row = w * 64 + ct * 16 + l15;                               \
                int pc  = (ks * 4 + quad) ^ (l15 & 7);                          \
                vf[ct] = *(const bf16x8*)&Vs[CUR][row * 64 + pc * 8];           \
            }                                                                   \
            __builtin_amdgcn_s_setprio(1);                                      \
            _Pragma("unroll")                                                   \
            for (int rt = 0; rt < 4; rt++)                                      \
                _Pragma("unroll")                                               \
                for (int ct = 0; ct < 4; ct++)                                  \
                    acc[rt][ct] = __builtin_amdgcn_mfma_f32_16x16x32_bf16(      \
                        pf[rt], vf[ct], acc[rt][ct], 0, 0, 0);                  \
            __builtin_amdgcn_s_setprio(0);                                      \
        }                                                                       \
    }

    for (int jt = 0; jt < NJ; jt += 2) {
        FLASH_ITER(jt,     0, kfB, kfA)
        FLASH_ITER(jt + 1, 1, kfA, kfB)
    }
#undef FLASH_ITER

    // final row-sum reduction across l15
#pragma unroll
    for (int r = 0; r < 4; r++) {
        float l = l_loc[r];
        l += __shfl_xor(l, 1);
        l += __shfl_xor(l, 2);
        l += __shfl_xor(l, 4);
        l += __shfl_xor(l, 8);
        l_loc[r] = l;
    }
    if (l15 == 0) {
        f32x4 lv = {l_loc[0], l_loc[1], l_loc[2], l_loc[3]};
        *(f32x4*)&Lrow[w * 16 + quad * 4] = lv;
    }
    __syncthreads();

    // epilogue: normalize, gamma, residual, coalesced [C][N] store
    for (int rt = 0; rt < 4; rt++) {
        f32x4 lv = *(f32x4*)&Lrow[rt * 16 + quad * 4];
        f32x4 gi;
#pragma unroll
        for (int r = 0; r < 4; r++) gi[r] = gamma / lv[r];
#pragma unroll
        for (int ct = 0; ct < 4; ct++) {
            int c = w * 64 + ct * 16 + l15;
            f32x4 ov;
#pragma unroll
            for (int r = 0; r < 4; r++) ov[r] = acc[rt][ct][r] * gi[r];
            *(f32x4*)&Ob[c * 20 + quad * 4] = ov;
        }
        __syncthreads();
#pragma unroll
        for (int rep = 0; rep < 4; rep++) {
            int c  = rep * 64 + (t >> 2);
            int p4 = t & 3;
            f32x4 v = *(f32x4*)&Ob[c * 20 + p4 * 4];
            size_t go = ((size_t)b * CC + c) * NN + i0 + rt * 16 + p4 * 4;
            f32x4 r4 = *(const f32x4*)&res[go];
            v += r4;
            *(f32x4*)&op[(size_t)c * NN + i0 + rt * 16 + p4 * 4] = v;
        }
        __syncthreads();
    }
}

extern "C" void kernel_launch(void* const* d_in, const int* in_sizes, int n_in,
                              void* d_out, int out_size, void* d_ws, size_t ws_size,
                              hipStream_t stream)
{
    const float* x   = (const float*)d_in[0];
    const float* y   = (const float*)d_in[1];
    const float* wqx = (const float*)d_in[2];
    const float* bqx = (const float*)d_in[3];
    const float* wkx = (const float*)d_in[4];
    const float* bkx = (const float*)d_in[5];
    const float* wvx = (const float*)d_in[6];
    const float* bvx = (const float*)d_in[7];
    const float* wqy = (const float*)d_in[8];
    const float* bqy = (const float*)d_in[9];
    const float* wky = (const float*)d_in[10];
    const float* bky = (const float*)d_in[11];
    const float* wvy = (const float*)d_in[12];
    const float* bvy = (const float*)d_in[13];
    const float* gx  = (const float*)d_in[14];
    const float* gy  = (const float*)d_in[15];
    ushort_t* ws = (ushort_t*)d_ws;
    float* out = (float*)d_out;

    wcvt_kernel<<<dim3(160), 256, 0, stream>>>(wqx, bqx, wkx, bkx, wvx, bvx,
                                               wqy, bqy, wky, bky, wvy, bvy, ws);
    proj_kernel<<<dim3(576), 256, 0, stream>>>(x, y, ws);
    flash_kernel<<<dim3(576), 256, 0, stream>>>(x, y, gx, gy, ws, out);
}